// Round 14
// baseline (269.482 us; speedup 1.0000x reference)
//
#include <hip/hip_runtime.h>

typedef unsigned short u16;
typedef unsigned int u32;
typedef __bf16 bf16x8 __attribute__((ext_vector_type(8)));
typedef float f32x4 __attribute__((ext_vector_type(4)));
typedef u16 u16x4 __attribute__((ext_vector_type(4)));
typedef u16 u16x8 __attribute__((ext_vector_type(8)));
typedef u32 u32x4 __attribute__((ext_vector_type(4)));

#define T_SEQ 2048
#define DMODEL 2048
#define NQKV 6144
#define HD 128
#define NH 16
#define MROWS 4096

__device__ __forceinline__ u16 f2b(float f) {
  union { float f; u32 u; } a; a.f = f;
  u32 r = a.u + 0x7fffu + ((a.u >> 16) & 1u);
  return (u16)(r >> 16);
}
__device__ __forceinline__ float b2f(u16 h) {
  union { u32 u; float f; } a; a.u = ((u32)h) << 16;
  return a.f;
}
__device__ __forceinline__ void g2l16(const u16* g, u16* l) {
  __builtin_amdgcn_global_load_lds((const __attribute__((address_space(1))) u32*)g,
                                   (__attribute__((address_space(3))) u32*)l, 16, 0, 0);
}

__global__ void k_f32_to_bf16(const float* __restrict__ in, u16* __restrict__ out, int n) {
  int i = (blockIdx.x * 256 + threadIdx.x) * 8;
  if (i >= n) return;
  float4 a = *(const float4*)(in + i);
  float4 b = *(const float4*)(in + i + 4);
  u16x8 v;
  v[0] = f2b(a.x); v[1] = f2b(a.y); v[2] = f2b(a.z); v[3] = f2b(a.w);
  v[4] = f2b(b.x); v[5] = f2b(b.y); v[6] = f2b(b.z); v[7] = f2b(b.w);
  *(u16x8*)(out + i) = v;
}

// out[c][r] = bf16(in[r][c]); in is R x C f32
__global__ void k_transpose_bf16(const float* __restrict__ in, u16* __restrict__ out,
                                 int R, int C) {
  __shared__ u16 tile[32][33];
  const int c0 = blockIdx.x * 32, r0 = blockIdx.y * 32;
  const int tx = threadIdx.x & 31, ty = threadIdx.x >> 5;
#pragma unroll
  for (int i = 0; i < 32; i += 8)
    tile[ty + i][tx] = f2b(in[(size_t)(r0 + ty + i) * C + c0 + tx]);
  __syncthreads();
#pragma unroll
  for (int i = 0; i < 32; i += 8)
    out[(size_t)(c0 + ty + i) * R + r0 + tx] = tile[tx][ty + i];
}

// ---------------------------------------------------------------------------
// QKV GEMM with fused RoPE + head-scatter epilogue (m97 128x128 structure).
// ROUND-11 VERSION (best measured: 136.8us) — gemm_qkv line CLOSED (r8-r12
// history in journal: occupancy attributes spill acc; LDS-bounce neutral).
// ---------------------------------------------------------------------------
__global__ __launch_bounds__(256) void k_gemm_qkv(const u16* __restrict__ A,
                                                  const u16* __restrict__ B,
                                                  u16* __restrict__ qr,
                                                  u16* __restrict__ kr,
                                                  u16* __restrict__ vtb) {
  __shared__ __align__(16) u16 lA[128 * 64];
  __shared__ __align__(16) u16 lB[128 * 64];
  const int K = DMODEL;
  const int tid = threadIdx.x;
  const int wid = tid >> 6, lane = tid & 63;
  const int g = lane >> 4, q = lane & 15;
  const int wr = wid >> 1, wc = wid & 1;
  const int bn = blockIdx.x, bm = blockIdx.y;
  const int l8 = lane >> 3, l7 = lane & 7;
  const f32x4 fzero = {0.f, 0.f, 0.f, 0.f};
  f32x4 acc[4][4];
#pragma unroll
  for (int m = 0; m < 4; ++m)
#pragma unroll
    for (int n = 0; n < 4; ++n) acc[m][n] = fzero;

  const u16* Ab = A + (size_t)bm * 128 * K;
  const u16* Bb = B + (size_t)bn * 128 * K;

  for (int k0 = 0; k0 < K; k0 += 64) {
    __syncthreads();
#pragma unroll
    for (int i = 0; i < 4; ++i) {
      int chunk = wid * 4 + i;
      int row = chunk * 8 + l8;
      int scol = (l7 * 8) ^ ((row & 7) << 3);
      g2l16(Ab + (size_t)row * K + k0 + scol, lA + chunk * 512);
      g2l16(Bb + (size_t)row * K + k0 + scol, lB + chunk * 512);
    }
    __syncthreads();
#pragma unroll
    for (int kk = 0; kk < 2; ++kk) {
      bf16x8 af[4], bfr[4];
#pragma unroll
      for (int m = 0; m < 4; ++m) {
        int row = wr * 64 + m * 16 + q;
        int col = (kk * 32 + g * 8) ^ ((row & 7) << 3);
        af[m] = *(const bf16x8*)(lA + row * 64 + col);
      }
#pragma unroll
      for (int n = 0; n < 4; ++n) {
        int row = wc * 32 + (n & 1) * 16 + (n >> 1) * 64 + q;  // paired-col mapping
        int col = (kk * 32 + g * 8) ^ ((row & 7) << 3);
        bfr[n] = *(const bf16x8*)(lB + row * 64 + col);
      }
#pragma unroll
      for (int m = 0; m < 4; ++m)
#pragma unroll
        for (int n = 0; n < 4; ++n)
          acc[m][n] = __builtin_amdgcn_mfma_f32_16x16x32_bf16(af[m], bfr[n], acc[m][n], 0, 0, 0);
    }
  }
  __builtin_amdgcn_sched_barrier(0);

  // ---- fused epilogue (fully unrolled; on-the-fly sincos) ----
  const int h = bn & 15;
  const int which = bn >> 4;                 // 0=q, 1=k, 2=v
  const int b = bm >> 4;
  const int bh = b * 16 + h;
  const int tb0 = (bm & 15) * 128 + wr * 64; // + m*16 + g*4 + r -> token idx
  const float qscale = 0.08838834764831845f;

  if (which == 2) {
    // V: store transposed to vtb[bh][d][t]; 4 consecutive t packed per store.
    u16* vdst = vtb + (size_t)bh * HD * T_SEQ;
#pragma unroll
    for (int m = 0; m < 4; ++m)
#pragma unroll
      for (int n = 0; n < 4; ++n) {
        int c = wc * 32 + (n & 1) * 16 + (n >> 1) * 64 + q;
        int t0 = tb0 + m * 16 + g * 4;
        u16x4 pk;
#pragma unroll
        for (int r = 0; r < 4; ++r) pk[r] = f2b(acc[m][n][r]);
        *(u16x4*)(vdst + (size_t)c * T_SEQ + t0) = pk;
      }
  } else {
    u16* dst = (which ? kr : qr) + (size_t)bh * T_SEQ * HD;
    const float sc = which ? 1.0f : qscale;
#pragma unroll
    for (int n = 0; n < 2; ++n) {
      int dm = wc * 32 + n * 16 + q;        // d % 64
      // inv_freq = 10000^(-dm/64) = exp2(-dm * log2(10000)/64)
      float inv = exp2f(-(float)dm * 0.20762050592046521f);
#pragma unroll
      for (int m = 0; m < 4; ++m)
#pragma unroll
        for (int r = 0; r < 4; ++r) {
          int t = tb0 + m * 16 + g * 4 + r;
          float s, c;
          __sincosf((float)t * inv, &s, &c);
          float x0 = acc[m][n][r];          // d = dm (low half)
          float x1 = acc[m][n + 2][r];      // d = dm + 64 (high half)
          u32 pk = (u32)f2b((x0 * c - x1 * s) * sc) |
                   ((u32)f2b((x1 * c + x0 * s) * sc) << 16);
          *(u32*)(dst + (size_t)t * HD + dm * 2) = pk;  // interleaved d
        }
    }
  }
}

// m97-style 128x128 GEMM for the output projection (EPI=1: f32 out).
template <int EPI>
__global__ __launch_bounds__(256) void k_gemm_nt(const u16* __restrict__ A,
                                                 const u16* __restrict__ B,
                                                 void* __restrict__ Cv,
                                                 int M, int N, int K) {
  __shared__ __align__(16) u16 lA[128 * 64];
  __shared__ __align__(16) u16 lB[128 * 64];
  const int tid = threadIdx.x;
  const int wid = tid >> 6, lane = tid & 63;
  const int g = lane >> 4, q = lane & 15;
  const int wr = wid >> 1, wc = wid & 1;
  const int bn = blockIdx.x, bm = blockIdx.y;
  const int l8 = lane >> 3, l7 = lane & 7;
  const f32x4 fzero = {0.f, 0.f, 0.f, 0.f};
  f32x4 acc[4][4];
#pragma unroll
  for (int m = 0; m < 4; ++m)
#pragma unroll
    for (int n = 0; n < 4; ++n) acc[m][n] = fzero;

  const u16* Ab = A + (size_t)bm * 128 * K;
  const u16* Bb = B + (size_t)bn * 128 * K;

  for (int k0 = 0; k0 < K; k0 += 64) {
    __syncthreads();
#pragma unroll
    for (int i = 0; i < 4; ++i) {
      int chunk = wid * 4 + i;
      int row = chunk * 8 + l8;
      int scol = (l7 * 8) ^ ((row & 7) << 3);
      g2l16(Ab + (size_t)row * K + k0 + scol, lA + chunk * 512);
      g2l16(Bb + (size_t)row * K + k0 + scol, lB + chunk * 512);
    }
    __syncthreads();
#pragma unroll
    for (int kk = 0; kk < 2; ++kk) {
      bf16x8 af[4], bfr[4];
#pragma unroll
      for (int m = 0; m < 4; ++m) {
        int row = wr * 64 + m * 16 + q;
        int col = (kk * 32 + g * 8) ^ ((row & 7) << 3);
        af[m] = *(const bf16x8*)(lA + row * 64 + col);
      }
#pragma unroll
      for (int n = 0; n < 4; ++n) {
        int row = wc * 64 + n * 16 + q;
        int col = (kk * 32 + g * 8) ^ ((row & 7) << 3);
        bfr[n] = *(const bf16x8*)(lB + row * 64 + col);
      }
#pragma unroll
      for (int m = 0; m < 4; ++m)
#pragma unroll
        for (int n = 0; n < 4; ++n)
          acc[m][n] = __builtin_amdgcn_mfma_f32_16x16x32_bf16(af[m], bfr[n], acc[m][n], 0, 0, 0);
    }
  }
  const int rbase = bm * 128 + wr * 64;
  const int cbase = bn * 128 + wc * 64;
#pragma unroll
  for (int m = 0; m < 4; ++m)
#pragma unroll
    for (int n = 0; n < 4; ++n) {
      int col = cbase + n * 16 + q;
#pragma unroll
      for (int r = 0; r < 4; ++r) {
        int row = rbase + m * 16 + g * 4 + r;
        if (EPI == 0)
          ((u16*)Cv)[(size_t)row * N + col] = f2b(acc[m][n][r]);
        else
          ((float*)Cv)[(size_t)row * N + col] = acc[m][n][r];
      }
    }
}

// Flash attention, triangle-folded at QBLK=64, grid (32 bh, 16): block does
// q-tile pair (31-y, y) = 33 k-tiles uniformly. Double-buffered K/V staging;
// diagonal-only causal mask; defer-max (T13). NEW (r14): IN-REGISTER P
// redistribution (T12-adapted) — p[m][r] (lane g,q = P[q][m*16+g*4+r]) is
// packed to bf16 pairs pw[m][rp], then PV's A-fragment word w for k =
// ks*32+g*8+2w comes from lane ((g&1)*2+(w>>1))*16+q, word pw[2ks+(g>>1)]
// [w&1]: 2 shfls + 1 select per word (pw indices compile-time, rule #20
// safe). Removes the P LDS roundtrip + drain from the critical path.
// No XCD swizzle (r13 bundle regressed). setprio kept (m191 attn-verified).
__global__ __launch_bounds__(256) void k_attn(const u16* __restrict__ qr,
                                              const u16* __restrict__ kr,
                                              const u16* __restrict__ vtb,
                                              u16* __restrict__ ao) {
  __shared__ __align__(16) u16 lK[2][64 * 128];
  __shared__ __align__(16) u16 lV[2][128 * 64];
  const int bh = blockIdx.x, b = bh >> 4, h = bh & 15;
  const int tid = threadIdx.x;
  const int wid = tid >> 6, lane = tid & 63;
  const int g = lane >> 4, q = lane & 15;
  const int l8 = lane >> 3, l7 = lane & 7;
  const u16* qb = qr + (size_t)bh * T_SEQ * HD;
  const u16* kbp = kr + (size_t)bh * T_SEQ * HD;
  const u16* vb = vtb + (size_t)bh * HD * T_SEQ;
  const f32x4 fzero = {0.f, 0.f, 0.f, 0.f};

  auto stageKV = [&](int kb, int bufI) {
#pragma unroll
    for (int i = 0; i < 4; ++i) {
      int chunk = wid * 4 + i;
      int row = chunk * 4 + g;
      int scol = (q * 8) ^ ((row & 7) << 3);
      g2l16(kbp + (size_t)(kb + row) * HD + scol, &lK[bufI][chunk * 512]);
    }
#pragma unroll
    for (int i = 0; i < 4; ++i) {
      int chunk = wid * 4 + i;
      int row = chunk * 8 + l8;
      int scol = (l7 * 8) ^ ((row & 7) << 3);
      g2l16(vb + (size_t)row * T_SEQ + kb + scol, &lV[bufI][chunk * 512]);
    }
  };

  for (int half = 0; half < 2; ++half) {
    const int qt = half ? (int)blockIdx.y : 31 - (int)blockIdx.y;
    const int qw0 = qt * 64 + wid * 16;

    bf16x8 qf[4];
#pragma unroll
    for (int ks = 0; ks < 4; ++ks)
      qf[ks] = *(const bf16x8*)(qb + (size_t)(qw0 + q) * HD + ks * 32 + g * 8);

    f32x4 o_acc[8];
#pragma unroll
    for (int n = 0; n < 8; ++n) o_acc[n] = fzero;
    float m_run = -1e30f, l_run = 0.f;

    const int ntiles = qt + 1;
    stageKV(0, 0);
    __syncthreads();                 // drains vmcnt -> buf0 ready
    for (int kt = 0; kt < ntiles; ++kt) {
      const int kb = kt * 64;
      const int cb = kt & 1;
      if (kt + 1 < ntiles) stageKV(kb + 64, cb ^ 1);   // prefetch next tile
      const u16* lKc = lK[cb];
      const u16* lVc = lV[cb];
      {
        f32x4 st[4];
#pragma unroll
        for (int m = 0; m < 4; ++m) st[m] = fzero;
        __builtin_amdgcn_s_setprio(1);
#pragma unroll
        for (int ks = 0; ks < 4; ++ks) {
#pragma unroll
          for (int m = 0; m < 4; ++m) {
            int row = m * 16 + q;
            int col = (ks * 32 + g * 8) ^ ((row & 7) << 3);
            bf16x8 kf = *(const bf16x8*)(lKc + row * 128 + col);
            st[m] = __builtin_amdgcn_mfma_f32_16x16x32_bf16(kf, qf[ks], st[m], 0, 0, 0);
          }
        }
        __builtin_amdgcn_s_setprio(0);
        const int qrow = qw0 + q;
        float p[4][4];
        float pmax = -1e30f;
        if (kt == ntiles - 1) {
          // diagonal tile: causal mask
#pragma unroll
          for (int m = 0; m < 4; ++m)
#pragma unroll
            for (int r = 0; r < 4; ++r) {
              int kcol = kb + m * 16 + g * 4 + r;
              float s = (kcol <= qrow) ? st[m][r] : -1e30f;
              p[m][r] = s;
              pmax = fmaxf(pmax, s);
            }
        } else {
#pragma unroll
          for (int m = 0; m < 4; ++m)
#pragma unroll
            for (int r = 0; r < 4; ++r) {
              p[m][r] = st[m][r];
              pmax = fmaxf(pmax, st[m][r]);
            }
        }
        pmax = fmaxf(pmax, __shfl_xor(pmax, 16));
        pmax = fmaxf(pmax, __shfl_xor(pmax, 32));
        // defer-max (T13, THR=0): skip rescale when no lane's max grew.
        const bool noresc = __all(pmax <= m_run);
        const float m_new = noresc ? m_run : fmaxf(m_run, pmax);
        float ls = 0.f;
#pragma unroll
        for (int m = 0; m < 4; ++m)
#pragma unroll
          for (int r = 0; r < 4; ++r) {
            float e = __expf(p[m][r] - m_new);
            p[m][r] = e;
            ls += e;
          }
        ls += __shfl_xor(ls, 16);
        ls += __shfl_xor(ls, 32);
        // pack P to bf16 pairs (same values the old lP path stored)
        u32 pw[4][2];
#pragma unroll
        for (int m = 0; m < 4; ++m)
#pragma unroll
          for (int rp = 0; rp < 2; ++rp)
            pw[m][rp] = (u32)f2b(p[m][rp * 2]) | ((u32)f2b(p[m][rp * 2 + 1]) << 16);
        if (noresc) {
          l_run += ls;
        } else {
          float corr = __expf(m_run - m_new);
          l_run = l_run * corr + ls;
          m_run = m_new;
          float corr4[4];
#pragma unroll
          for (int r = 0; r < 4; ++r) corr4[r] = __shfl(corr, g * 4 + r);
#pragma unroll
          for (int n = 0; n < 8; ++n) {
#pragma unroll
            for (int r = 0; r < 4; ++r) o_acc[n][r] *= corr4[r];
          }
        }
        // PV with in-register P redistribution
        const bool ghi = (g >= 2);
#pragma unroll
        for (int ks = 0; ks < 2; ++ks) {
          union { u32x4 w; bf16x8 v; } pfu;
#pragma unroll
          for (int w = 0; w < 4; ++w) {
            int sgl = ((g & 1) * 2 + (w >> 1)) * 16 + q;
            u32 wa = (u32)__shfl((int)pw[2 * ks][w & 1], sgl, 64);
            u32 wb = (u32)__shfl((int)pw[2 * ks + 1][w & 1], sgl, 64);
            pfu.w[w] = ghi ? wb : wa;
          }
          bf16x8 pf = pfu.v;
          __builtin_amdgcn_s_setprio(1);
#pragma unroll
          for (int n = 0; n < 8; ++n) {
            int row = n * 16 + q;
            int col = (ks * 32 + g * 8) ^ ((row & 7) << 3);
            bf16x8 vf = *(const bf16x8*)(lVc + row * 64 + col);
            o_acc[n] = __builtin_amdgcn_mfma_f32_16x16x32_bf16(pf, vf, o_acc[n], 0, 0, 0);
          }
          __builtin_amdgcn_s_setprio(0);
        }
      }
      __syncthreads();               // drains vmcnt: prefetched buf ready; LDS reads done
    }
    float linv[4];
#pragma unroll
    for (int r = 0; r < 4; ++r) {
      float lv = __shfl(l_run, g * 4 + r);
      linv[r] = 1.0f / lv;
    }
#pragma unroll
    for (int n = 0; n < 8; ++n)
#pragma unroll
      for (int r = 0; r < 4; ++r) {
        int trow = qw0 + g * 4 + r;
        ao[(size_t)(b * T_SEQ + trow) * DMODEL + h * HD + n * 16 + q] = f2b(o_acc[n][r] * linv[r]);
      }
  }
}

extern "C" void kernel_launch(void* const* d_in, const int* in_sizes, int n_in,
                              void* d_out, int out_size, void* d_ws, size_t ws_size,
                              hipStream_t stream) {
  const float* x = (const float*)d_in[0];
  const float* w_qkv = (const float*)d_in[1];
  const float* w_out = (const float*)d_in[2];
  char* ws = (char*)d_ws;
  size_t off = 0;
  u16* xb = (u16*)(ws + off);    off += (size_t)MROWS * DMODEL * 2;   // also reused as ao
  u16* wqkvT = (u16*)(ws + off); off += (size_t)NQKV * DMODEL * 2;
  u16* woutT = (u16*)(ws + off); off += (size_t)DMODEL * DMODEL * 2;
  u16* qr = (u16*)(ws + off);    off += (size_t)32 * T_SEQ * HD * 2;
  u16* kr = (u16*)(ws + off);    off += (size_t)32 * T_SEQ * HD * 2;
  u16* vtb = (u16*)(ws + off);   off += (size_t)32 * T_SEQ * HD * 2;
  u16* ao = xb;

  k_f32_to_bf16<<<dim3(MROWS * DMODEL / (256 * 8)), 256, 0, stream>>>(x, xb, MROWS * DMODEL);
  k_transpose_bf16<<<dim3(NQKV / 32, DMODEL / 32), 256, 0, stream>>>(w_qkv, wqkvT, DMODEL, NQKV);
  k_transpose_bf16<<<dim3(DMODEL / 32, DMODEL / 32), 256, 0, stream>>>(w_out, woutT, DMODEL, DMODEL);
  k_gemm_qkv<<<dim3(48, 32), 256, 0, stream>>>(xb, wqkvT, qr, kr, vtb);
  k_attn<<<dim3(32, 16), 256, 0, stream>>>(qr, kr, vtb, ao);
  k_gemm_nt<1><<<dim3(DMODEL / 128, MROWS / 128), 256, 0, stream>>>(ao, woutT, d_out, MROWS, DMODEL, DMODEL);
}

// Round 15
// 263.543 us; speedup vs baseline: 1.0225x; 1.0225x over previous
//
#include <hip/hip_runtime.h>

typedef unsigned short u16;
typedef unsigned int u32;
typedef __bf16 bf16x8 __attribute__((ext_vector_type(8)));
typedef float f32x4 __attribute__((ext_vector_type(4)));
typedef u16 u16x4 __attribute__((ext_vector_type(4)));
typedef u16 u16x8 __attribute__((ext_vector_type(8)));

#define T_SEQ 2048
#define DMODEL 2048
#define NQKV 6144
#define HD 128
#define NH 16
#define MROWS 4096

__device__ __forceinline__ u16 f2b(float f) {
  union { float f; u32 u; } a; a.f = f;
  u32 r = a.u + 0x7fffu + ((a.u >> 16) & 1u);
  return (u16)(r >> 16);
}
__device__ __forceinline__ float b2f(u16 h) {
  union { u32 u; float f; } a; a.u = ((u32)h) << 16;
  return a.f;
}
__device__ __forceinline__ void g2l16(const u16* g, u16* l) {
  __builtin_amdgcn_global_load_lds((const __attribute__((address_space(1))) u32*)g,
                                   (__attribute__((address_space(3))) u32*)l, 16, 0, 0);
}

__global__ void k_f32_to_bf16(const float* __restrict__ in, u16* __restrict__ out, int n) {
  int i = (blockIdx.x * 256 + threadIdx.x) * 8;
  if (i >= n) return;
  float4 a = *(const float4*)(in + i);
  float4 b = *(const float4*)(in + i + 4);
  u16x8 v;
  v[0] = f2b(a.x); v[1] = f2b(a.y); v[2] = f2b(a.z); v[3] = f2b(a.w);
  v[4] = f2b(b.x); v[5] = f2b(b.y); v[6] = f2b(b.z); v[7] = f2b(b.w);
  *(u16x8*)(out + i) = v;
}

// out[c][r] = bf16(in[r][c]); in is R x C f32
__global__ void k_transpose_bf16(const float* __restrict__ in, u16* __restrict__ out,
                                 int R, int C) {
  __shared__ u16 tile[32][33];
  const int c0 = blockIdx.x * 32, r0 = blockIdx.y * 32;
  const int tx = threadIdx.x & 31, ty = threadIdx.x >> 5;
#pragma unroll
  for (int i = 0; i < 32; i += 8)
    tile[ty + i][tx] = f2b(in[(size_t)(r0 + ty + i) * C + c0 + tx]);
  __syncthreads();
#pragma unroll
  for (int i = 0; i < 32; i += 8)
    out[(size_t)(c0 + ty + i) * R + r0 + tx] = tile[tx][ty + i];
}

// ---------------------------------------------------------------------------
// QKV GEMM with fused RoPE + head-scatter epilogue (m97 128x128 structure).
// ROUND-11 VERSION (best measured: 136.8us) — gemm_qkv line CLOSED:
// r8 launch_bounds(,6) ignored; r9 waves_per_eu(5) spilled acc (678MB);
// r10 unroll-1 runtime-indexed acc (3GB scratch, rule #20); r12 LDS-bounce
// cut VGPR 120->96 but occupancy didn't respond. Fused (136.8) == split
// (116.6 + 18 scatter): the epilogue cost is inherent work, not overhead.
// q/k stored with interleaved d-permutation (d<64->2d, d>=64->2(d-64)+1);
// QK^T invariant since Q,K share it. V transposed to vtb[bh][d][t].
// ---------------------------------------------------------------------------
__global__ __launch_bounds__(256) void k_gemm_qkv(const u16* __restrict__ A,
                                                  const u16* __restrict__ B,
                                                  u16* __restrict__ qr,
                                                  u16* __restrict__ kr,
                                                  u16* __restrict__ vtb) {
  __shared__ __align__(16) u16 lA[128 * 64];
  __shared__ __align__(16) u16 lB[128 * 64];
  const int K = DMODEL;
  const int tid = threadIdx.x;
  const int wid = tid >> 6, lane = tid & 63;
  const int g = lane >> 4, q = lane & 15;
  const int wr = wid >> 1, wc = wid & 1;
  const int bn = blockIdx.x, bm = blockIdx.y;
  const int l8 = lane >> 3, l7 = lane & 7;
  const f32x4 fzero = {0.f, 0.f, 0.f, 0.f};
  f32x4 acc[4][4];
#pragma unroll
  for (int m = 0; m < 4; ++m)
#pragma unroll
    for (int n = 0; n < 4; ++n) acc[m][n] = fzero;

  const u16* Ab = A + (size_t)bm * 128 * K;
  const u16* Bb = B + (size_t)bn * 128 * K;

  for (int k0 = 0; k0 < K; k0 += 64) {
    __syncthreads();
#pragma unroll
    for (int i = 0; i < 4; ++i) {
      int chunk = wid * 4 + i;
      int row = chunk * 8 + l8;
      int scol = (l7 * 8) ^ ((row & 7) << 3);
      g2l16(Ab + (size_t)row * K + k0 + scol, lA + chunk * 512);
      g2l16(Bb + (size_t)row * K + k0 + scol, lB + chunk * 512);
    }
    __syncthreads();
#pragma unroll
    for (int kk = 0; kk < 2; ++kk) {
      bf16x8 af[4], bfr[4];
#pragma unroll
      for (int m = 0; m < 4; ++m) {
        int row = wr * 64 + m * 16 + q;
        int col = (kk * 32 + g * 8) ^ ((row & 7) << 3);
        af[m] = *(const bf16x8*)(lA + row * 64 + col);
      }
#pragma unroll
      for (int n = 0; n < 4; ++n) {
        int row = wc * 32 + (n & 1) * 16 + (n >> 1) * 64 + q;  // paired-col mapping
        int col = (kk * 32 + g * 8) ^ ((row & 7) << 3);
        bfr[n] = *(const bf16x8*)(lB + row * 64 + col);
      }
#pragma unroll
      for (int m = 0; m < 4; ++m)
#pragma unroll
        for (int n = 0; n < 4; ++n)
          acc[m][n] = __builtin_amdgcn_mfma_f32_16x16x32_bf16(af[m], bfr[n], acc[m][n], 0, 0, 0);
    }
  }
  __builtin_amdgcn_sched_barrier(0);

  // ---- fused epilogue (fully unrolled; on-the-fly sincos) ----
  const int h = bn & 15;
  const int which = bn >> 4;                 // 0=q, 1=k, 2=v
  const int b = bm >> 4;
  const int bh = b * 16 + h;
  const int tb0 = (bm & 15) * 128 + wr * 64; // + m*16 + g*4 + r -> token idx
  const float qscale = 0.08838834764831845f;

  if (which == 2) {
    // V: store transposed to vtb[bh][d][t]; 4 consecutive t packed per store.
    u16* vdst = vtb + (size_t)bh * HD * T_SEQ;
#pragma unroll
    for (int m = 0; m < 4; ++m)
#pragma unroll
      for (int n = 0; n < 4; ++n) {
        int c = wc * 32 + (n & 1) * 16 + (n >> 1) * 64 + q;
        int t0 = tb0 + m * 16 + g * 4;
        u16x4 pk;
#pragma unroll
        for (int r = 0; r < 4; ++r) pk[r] = f2b(acc[m][n][r]);
        *(u16x4*)(vdst + (size_t)c * T_SEQ + t0) = pk;
      }
  } else {
    u16* dst = (which ? kr : qr) + (size_t)bh * T_SEQ * HD;
    const float sc = which ? 1.0f : qscale;
#pragma unroll
    for (int n = 0; n < 2; ++n) {
      int dm = wc * 32 + n * 16 + q;        // d % 64
      // inv_freq = 10000^(-dm/64) = exp2(-dm * log2(10000)/64)
      float inv = exp2f(-(float)dm * 0.20762050592046521f);
#pragma unroll
      for (int m = 0; m < 4; ++m)
#pragma unroll
        for (int r = 0; r < 4; ++r) {
          int t = tb0 + m * 16 + g * 4 + r;
          float s, c;
          __sincosf((float)t * inv, &s, &c);
          float x0 = acc[m][n][r];          // d = dm (low half)
          float x1 = acc[m][n + 2][r];      // d = dm + 64 (high half)
          u32 pk = (u32)f2b((x0 * c - x1 * s) * sc) |
                   ((u32)f2b((x1 * c + x0 * s) * sc) << 16);
          *(u32*)(dst + (size_t)t * HD + dm * 2) = pk;  // interleaved d
        }
    }
  }
}

// m97-style 128x128 GEMM for the output projection (EPI=1: f32 out).
template <int EPI>
__global__ __launch_bounds__(256) void k_gemm_nt(const u16* __restrict__ A,
                                                 const u16* __restrict__ B,
                                                 void* __restrict__ Cv,
                                                 int M, int N, int K) {
  __shared__ __align__(16) u16 lA[128 * 64];
  __shared__ __align__(16) u16 lB[128 * 64];
  const int tid = threadIdx.x;
  const int wid = tid >> 6, lane = tid & 63;
  const int g = lane >> 4, q = lane & 15;
  const int wr = wid >> 1, wc = wid & 1;
  const int bn = blockIdx.x, bm = blockIdx.y;
  const int l8 = lane >> 3, l7 = lane & 7;
  const f32x4 fzero = {0.f, 0.f, 0.f, 0.f};
  f32x4 acc[4][4];
#pragma unroll
  for (int m = 0; m < 4; ++m)
#pragma unroll
    for (int n = 0; n < 4; ++n) acc[m][n] = fzero;

  const u16* Ab = A + (size_t)bm * 128 * K;
  const u16* Bb = B + (size_t)bn * 128 * K;

  for (int k0 = 0; k0 < K; k0 += 64) {
    __syncthreads();
#pragma unroll
    for (int i = 0; i < 4; ++i) {
      int chunk = wid * 4 + i;
      int row = chunk * 8 + l8;
      int scol = (l7 * 8) ^ ((row & 7) << 3);
      g2l16(Ab + (size_t)row * K + k0 + scol, lA + chunk * 512);
      g2l16(Bb + (size_t)row * K + k0 + scol, lB + chunk * 512);
    }
    __syncthreads();
#pragma unroll
    for (int kk = 0; kk < 2; ++kk) {
      bf16x8 af[4], bfr[4];
#pragma unroll
      for (int m = 0; m < 4; ++m) {
        int row = wr * 64 + m * 16 + q;
        int col = (kk * 32 + g * 8) ^ ((row & 7) << 3);
        af[m] = *(const bf16x8*)(lA + row * 64 + col);
      }
#pragma unroll
      for (int n = 0; n < 4; ++n) {
        int row = wc * 64 + n * 16 + q;
        int col = (kk * 32 + g * 8) ^ ((row & 7) << 3);
        bfr[n] = *(const bf16x8*)(lB + row * 64 + col);
      }
#pragma unroll
      for (int m = 0; m < 4; ++m)
#pragma unroll
        for (int n = 0; n < 4; ++n)
          acc[m][n] = __builtin_amdgcn_mfma_f32_16x16x32_bf16(af[m], bfr[n], acc[m][n], 0, 0, 0);
    }
  }
  const int rbase = bm * 128 + wr * 64;
  const int cbase = bn * 128 + wc * 64;
#pragma unroll
  for (int m = 0; m < 4; ++m)
#pragma unroll
    for (int n = 0; n < 4; ++n) {
      int col = cbase + n * 16 + q;
#pragma unroll
      for (int r = 0; r < 4; ++r) {
        int row = rbase + m * 16 + g * 4 + r;
        if (EPI == 0)
          ((u16*)Cv)[(size_t)row * N + col] = f2b(acc[m][n][r]);
        else
          ((float*)Cv)[(size_t)row * N + col] = acc[m][n][r];
      }
    }
}

// Flash attention, triangle-folded at QBLK=64, grid (32 bh, 16): block does
// q-tile pair (31-y, y) = 33 k-tiles uniformly. Double-buffered K/V staging
// (prefetch next tile before compute; end-of-tile __syncthreads drains
// vmcnt after compute). Causal mask applied per-tile. ROUND-11 VERSION —
// best measured attn residual (127.4us incl. out-proj+preproc): r12
// defer-max neutral, r13 setprio/XCD-swizzle +2.4, r14 shfl-P +5.8.
__global__ __launch_bounds__(256) void k_attn(const u16* __restrict__ qr,
                                              const u16* __restrict__ kr,
                                              const u16* __restrict__ vtb,
                                              u16* __restrict__ ao) {
  __shared__ __align__(16) u16 lK[2][64 * 128];
  __shared__ __align__(16) u16 lV[2][128 * 64];
  __shared__ __align__(16) u16 lP[4][16 * 72];
  const int bh = blockIdx.x, b = bh >> 4, h = bh & 15;
  const int tid = threadIdx.x;
  const int wid = tid >> 6, lane = tid & 63;
  const int g = lane >> 4, q = lane & 15;
  const int l8 = lane >> 3, l7 = lane & 7;
  const u16* qb = qr + (size_t)bh * T_SEQ * HD;
  const u16* kbp = kr + (size_t)bh * T_SEQ * HD;
  const u16* vb = vtb + (size_t)bh * HD * T_SEQ;
  const f32x4 fzero = {0.f, 0.f, 0.f, 0.f};

  auto stageKV = [&](int kb, int bufI) {
#pragma unroll
    for (int i = 0; i < 4; ++i) {
      int chunk = wid * 4 + i;
      int row = chunk * 4 + g;
      int scol = (q * 8) ^ ((row & 7) << 3);
      g2l16(kbp + (size_t)(kb + row) * HD + scol, &lK[bufI][chunk * 512]);
    }
#pragma unroll
    for (int i = 0; i < 4; ++i) {
      int chunk = wid * 4 + i;
      int row = chunk * 8 + l8;
      int scol = (l7 * 8) ^ ((row & 7) << 3);
      g2l16(vb + (size_t)row * T_SEQ + kb + scol, &lV[bufI][chunk * 512]);
    }
  };

  for (int half = 0; half < 2; ++half) {
    const int qt = half ? (int)blockIdx.y : 31 - (int)blockIdx.y;
    const int qw0 = qt * 64 + wid * 16;

    bf16x8 qf[4];
#pragma unroll
    for (int ks = 0; ks < 4; ++ks)
      qf[ks] = *(const bf16x8*)(qb + (size_t)(qw0 + q) * HD + ks * 32 + g * 8);

    f32x4 o_acc[8];
#pragma unroll
    for (int n = 0; n < 8; ++n) o_acc[n] = fzero;
    float m_run = -1e30f, l_run = 0.f;

    const int ntiles = qt + 1;
    stageKV(0, 0);
    __syncthreads();                 // drains vmcnt -> buf0 ready
    for (int kt = 0; kt < ntiles; ++kt) {
      const int kb = kt * 64;
      const int cb = kt & 1;
      if (kt + 1 < ntiles) stageKV(kb + 64, cb ^ 1);   // prefetch next tile
      const u16* lKc = lK[cb];
      const u16* lVc = lV[cb];
      {
        f32x4 st[4];
#pragma unroll
        for (int m = 0; m < 4; ++m) st[m] = fzero;
#pragma unroll
        for (int ks = 0; ks < 4; ++ks) {
#pragma unroll
          for (int m = 0; m < 4; ++m) {
            int row = m * 16 + q;
            int col = (ks * 32 + g * 8) ^ ((row & 7) << 3);
            bf16x8 kf = *(const bf16x8*)(lKc + row * 128 + col);
            st[m] = __builtin_amdgcn_mfma_f32_16x16x32_bf16(kf, qf[ks], st[m], 0, 0, 0);
          }
        }
        const int qrow = qw0 + q;
        float p[4][4];
        float pmax = -1e30f;
        if (kt == ntiles - 1) {
          // diagonal tile: causal mask
#pragma unroll
          for (int m = 0; m < 4; ++m)
#pragma unroll
            for (int r = 0; r < 4; ++r) {
              int kcol = kb + m * 16 + g * 4 + r;
              float s = (kcol <= qrow) ? st[m][r] : -1e30f;
              p[m][r] = s;
              pmax = fmaxf(pmax, s);
            }
        } else {
#pragma unroll
          for (int m = 0; m < 4; ++m)
#pragma unroll
            for (int r = 0; r < 4; ++r) {
              p[m][r] = st[m][r];
              pmax = fmaxf(pmax, st[m][r]);
            }
        }
        pmax = fmaxf(pmax, __shfl_xor(pmax, 16));
        pmax = fmaxf(pmax, __shfl_xor(pmax, 32));
        float m_new = fmaxf(m_run, pmax);
        float corr = __expf(m_run - m_new);
        float ls = 0.f;
#pragma unroll
        for (int m = 0; m < 4; ++m)
#pragma unroll
          for (int r = 0; r < 4; ++r) {
            float e = __expf(p[m][r] - m_new);
            p[m][r] = e;
            ls += e;
          }
        ls += __shfl_xor(ls, 16);
        ls += __shfl_xor(ls, 32);
        l_run = l_run * corr + ls;
        m_run = m_new;
#pragma unroll
        for (int m = 0; m < 4; ++m) {
#pragma unroll
          for (int rp = 0; rp < 2; ++rp) {
            u32 pk = (u32)f2b(p[m][rp * 2]) | ((u32)f2b(p[m][rp * 2 + 1]) << 16);
            *(u32*)(&lP[wid][q * 72 + m * 16 + g * 4 + rp * 2]) = pk;
          }
        }
        asm volatile("s_waitcnt lgkmcnt(0)" ::: "memory");
        __builtin_amdgcn_sched_barrier(0);
        float corr4[4];
#pragma unroll
        for (int r = 0; r < 4; ++r) corr4[r] = __shfl(corr, g * 4 + r);
#pragma unroll
        for (int n = 0; n < 8; ++n) {
#pragma unroll
          for (int r = 0; r < 4; ++r) o_acc[n][r] *= corr4[r];
        }
#pragma unroll
        for (int ks = 0; ks < 2; ++ks) {
          bf16x8 pf = *(const bf16x8*)(&lP[wid][q * 72 + ks * 32 + g * 8]);
#pragma unroll
          for (int n = 0; n < 8; ++n) {
            int row = n * 16 + q;
            int col = (ks * 32 + g * 8) ^ ((row & 7) << 3);
            bf16x8 vf = *(const bf16x8*)(lVc + row * 64 + col);
            o_acc[n] = __builtin_amdgcn_mfma_f32_16x16x32_bf16(pf, vf, o_acc[n], 0, 0, 0);
          }
        }
      }
      __syncthreads();               // drains vmcnt: prefetched buf ready; LDS reads done
    }
    float linv[4];
#pragma unroll
    for (int r = 0; r < 4; ++r) {
      float lv = __shfl(l_run, g * 4 + r);
      linv[r] = 1.0f / lv;
    }
#pragma unroll
    for (int n = 0; n < 8; ++n)
#pragma unroll
      for (int r = 0; r < 4; ++r) {
        int trow = qw0 + g * 4 + r;
        ao[(size_t)(b * T_SEQ + trow) * DMODEL + h * HD + n * 16 + q] = f2b(o_acc[n][r] * linv[r]);
      }
  }
}

extern "C" void kernel_launch(void* const* d_in, const int* in_sizes, int n_in,
                              void* d_out, int out_size, void* d_ws, size_t ws_size,
                              hipStream_t stream) {
  const float* x = (const float*)d_in[0];
  const float* w_qkv = (const float*)d_in[1];
  const float* w_out = (const float*)d_in[2];
  char* ws = (char*)d_ws;
  size_t off = 0;
  u16* xb = (u16*)(ws + off);    off += (size_t)MROWS * DMODEL * 2;   // also reused as ao
  u16* wqkvT = (u16*)(ws + off); off += (size_t)NQKV * DMODEL * 2;
  u16* woutT = (u16*)(ws + off); off += (size_t)DMODEL * DMODEL * 2;
  u16* qr = (u16*)(ws + off);    off += (size_t)32 * T_SEQ * HD * 2;
  u16* kr = (u16*)(ws + off);    off += (size_t)32 * T_SEQ * HD * 2;
  u16* vtb = (u16*)(ws + off);   off += (size_t)32 * T_SEQ * HD * 2;
  u16* ao = xb;

  k_f32_to_bf16<<<dim3(MROWS * DMODEL / (256 * 8)), 256, 0, stream>>>(x, xb, MROWS * DMODEL);
  k_transpose_bf16<<<dim3(NQKV / 32, DMODEL / 32), 256, 0, stream>>>(w_qkv, wqkvT, DMODEL, NQKV);
  k_transpose_bf16<<<dim3(DMODEL / 32, DMODEL / 32), 256, 0, stream>>>(w_out, woutT, DMODEL, DMODEL);
  k_gemm_qkv<<<dim3(48, 32), 256, 0, stream>>>(xb, wqkvT, qr, kr, vtb);
  k_attn<<<dim3(32, 16), 256, 0, stream>>>(qr, kr, vtb, ao);
  k_gemm_nt<1><<<dim3(DMODEL / 128, MROWS / 128), 256, 0, stream>>>(ao, woutT, d_out, MROWS, DMODEL, DMODEL);
}